// Round 11
// baseline (57.796 us; speedup 1.0000x reference)
//
#include <hip/hip_runtime.h>
#include <hip/hip_bf16.h>

typedef unsigned short u16;
typedef __attribute__((ext_vector_type(8))) __bf16 bf16x8;
typedef __attribute__((ext_vector_type(4))) float f32x4;
typedef __attribute__((ext_vector_type(4))) unsigned short u16x4;
typedef __attribute__((ext_vector_type(4))) unsigned int u32x4;

#define DEV static __device__ __forceinline__

static constexpr int N = 2048, D = 1024;
static constexpr float EPS = 1e-5f;

DEV u16 f2b(float f) {
  union { float f; unsigned u; } x; x.f = f;
  unsigned r = x.u + 0x7FFFu + ((x.u >> 16) & 1u);   // RNE
  return (u16)(r >> 16);
}
DEV float b2f(u16 h) {
  union { unsigned u; float f; } x; x.u = ((unsigned)h) << 16;
  return x.f;
}

DEV void async16(const void* g, void* l) {
  __builtin_amdgcn_global_load_lds(
      (const __attribute__((address_space(1))) unsigned int*)g,
      (__attribute__((address_space(3))) unsigned int*)l, 16, 0, 0);
}

// ---- fused pre (round-6 form): blocks [0,2048) = LayerNorm(x)->bf16 AND out=x;
//                                [2048,6144) = transpose w -> bf16 [N][K]
__global__ __launch_bounds__(256) void k_pre(const float* __restrict__ x,
                                             const float* __restrict__ wq, const float* __restrict__ wk,
                                             const float* __restrict__ wv, const float* __restrict__ wo,
                                             u16* __restrict__ xn, u16* __restrict__ wt,
                                             float* __restrict__ out) {
  const int t = threadIdx.x;
  if (blockIdx.x < 2048) {
    const int row = blockIdx.x;
    const float4 v = ((const float4*)(x + (size_t)row * D))[t];
    ((float4*)(out + (size_t)row * D))[t] = v;      // residual base; rows<256 get atomic adds later
    float s  = v.x + v.y + v.z + v.w;
    float ss = v.x * v.x + v.y * v.y + v.z * v.z + v.w * v.w;
    __shared__ float red0[4], red1[4];
    for (int off = 32; off; off >>= 1) { s += __shfl_xor(s, off, 64); ss += __shfl_xor(ss, off, 64); }
    const int w = t >> 6, l = t & 63;
    if (l == 0) { red0[w] = s; red1[w] = ss; }
    __syncthreads();
    s  = red0[0] + red0[1] + red0[2] + red0[3];
    ss = red1[0] + red1[1] + red1[2] + red1[3];
    const float mu = s * (1.0f / D);
    const float var = ss * (1.0f / D) - mu * mu;
    const float rs = rsqrtf(var + EPS);
    u16x4 o;
    o.x = f2b((v.x - mu) * rs); o.y = f2b((v.y - mu) * rs);
    o.z = f2b((v.z - mu) * rs); o.w = f2b((v.w - mu) * rs);
    ((u16x4*)(xn + (size_t)row * D))[t] = o;
  } else {
    const int bid = blockIdx.x - 2048;
    const int z = bid >> 10, rem = bid & 1023;
    const float* src = z == 0 ? wq : z == 1 ? wk : z == 2 ? wv : wo;
    u16* dst = wt + (size_t)z * D * D;
    __shared__ float tile[32][33];
    const int k0 = (rem >> 5) * 32, n0 = (rem & 31) * 32;
    const int c = t & 31, r4 = t >> 5;
#pragma unroll
    for (int p = 0; p < 4; ++p) { int r = r4 + p * 8; tile[r][c] = src[(size_t)(k0 + r) * D + n0 + c]; }
    __syncthreads();
#pragma unroll
    for (int p = 0; p < 4; ++p) { int r = r4 + p * 8; dst[(size_t)(n0 + r) * D + k0 + c] = f2b(tile[c][r]); }
  }
}

// 64x64 bf16 MFMA GEMM tile, single-buffer 2-barrier (round-6 proven structure), templated BK.
// LDS swizzle: 16B chunk pos p of row R stores global k-chunk p^(R&7) (low-3 XOR; pre-swizzled
// global source for global_load_lds + XOR'd ds_read). Bank-quad pattern identical for BK=64/128.
// EPI: 1 = per-row LN over the 64 cols -> bf16; 2 = bf16 store; 3 = f32 atomicAdd
template<int EPI, int BK>
DEV void gemm64(u16* __restrict__ As, u16* __restrict__ Bs,
                const u16* __restrict__ A, const u16* __restrict__ BT,
                void* __restrict__ dst, int row0, int col0, int dcol0, int ldc,
                int kbeg, int kend) {
  constexpr int K = 1024;
  constexpr int CPR = BK / 8;            // 16B chunks per row
  constexpr int NP  = (64 * CPR) / 256;  // staging chunks per thread per panel
  constexpr int NKK = BK / 32;           // MFMA k-steps per iter
  const int t = threadIdx.x;
  const int w = t >> 6, l = t & 63;
  const int wm = w << 4;                 // wave's 16 output rows
  const int fr = l & 15, kg = l >> 4;
  const int rq = kg << 2;

  f32x4 acc[4];
#pragma unroll
  for (int j = 0; j < 4; ++j) acc[j] = (f32x4){0.f, 0.f, 0.f, 0.f};

  // staging: chunk c = t + p*256: row = c/CPR, stored pos = c%CPR, global chunk = pos^(row&7)
  const u16* gA[NP]; const u16* gB[NP];
#pragma unroll
  for (int p = 0; p < NP; ++p) {
    const int c = t + p * 256, row = c / CPR, pos = c % CPR;
    const int gc = pos ^ (row & 7);
    gA[p] = A  + (size_t)(row0 + row) * K + gc * 8;
    gB[p] = BT + (size_t)(col0 + row) * K + gc * 8;
  }

  for (int k0 = kbeg; k0 < kend; k0 += BK) {
#pragma unroll
    for (int p = 0; p < NP; ++p) {
      async16(gA[p] + k0, &As[(t + p * 256) * 8]);
      async16(gB[p] + k0, &Bs[(t + p * 256) * 8]);
    }
    __syncthreads();                       // drain vmcnt: staged data visible
    bf16x8 af[NKK], bf[4][NKK];
#pragma unroll
    for (int kk = 0; kk < NKK; ++kk)
      af[kk] = *(const bf16x8*)&As[(wm + fr) * BK + ((((kk << 2) + kg)) ^ (fr & 7)) * 8];
#pragma unroll
    for (int j = 0; j < 4; ++j)
#pragma unroll
      for (int kk = 0; kk < NKK; ++kk)
        bf[j][kk] = *(const bf16x8*)&Bs[(j * 16 + fr) * BK + (((kk << 2) + kg) ^ (fr & 7)) * 8];
#pragma unroll
    for (int kk = 0; kk < NKK; ++kk)
#pragma unroll
      for (int j = 0; j < 4; ++j)
        acc[j] = __builtin_amdgcn_mfma_f32_16x16x32_bf16(af[kk], bf[j][kk], acc[j], 0, 0, 0);
    __syncthreads();                       // LDS reads done before next stage overwrites
  }

  // C/D layout: col = j*16 + fr, row = wm + rq + r
  if constexpr (EPI == 1) {
    // per-row LN over this tile's 64 cols (tile == one head); width-16 shuffle reduce
    float ps[4], pss[4];
#pragma unroll
    for (int r = 0; r < 4; ++r) {
      float s = 0.f, ss = 0.f;
#pragma unroll
      for (int j = 0; j < 4; ++j) { const float v = acc[j][r]; s += v; ss += v * v; }
      ps[r] = s; pss[r] = ss;
    }
    for (int off = 1; off < 16; off <<= 1)
#pragma unroll
      for (int r = 0; r < 4; ++r) {
        ps[r]  += __shfl_xor(ps[r],  off, 16);
        pss[r] += __shfl_xor(pss[r], off, 16);
      }
    u16* o = (u16*)dst;
#pragma unroll
    for (int r = 0; r < 4; ++r) {
      const float mu = ps[r] * (1.0f / 64);
      const float rs = rsqrtf(pss[r] * (1.0f / 64) - mu * mu + EPS);
      const int row = row0 + wm + rq + r;
#pragma unroll
      for (int j = 0; j < 4; ++j)
        o[(size_t)row * ldc + dcol0 + j * 16 + fr] = f2b((acc[j][r] - mu) * rs);
    }
  } else if constexpr (EPI == 2) {
    u16* o = (u16*)dst;
#pragma unroll
    for (int r = 0; r < 4; ++r) {
      const int row = row0 + wm + rq + r;
#pragma unroll
      for (int j = 0; j < 4; ++j)
        o[(size_t)row * ldc + dcol0 + j * 16 + fr] = f2b(acc[j][r]);
    }
  } else {
    float* o = (float*)dst;
#pragma unroll
    for (int r = 0; r < 4; ++r) {
      const int row = row0 + wm + rq + r;
#pragma unroll
      for (int j = 0; j < 4; ++j)
        atomicAdd(&o[(size_t)row * ldc + dcol0 + j * 16 + fr], acc[j][r]);
    }
  }
}

// fused QKV (round-6 grid, BK=128): [0,1024) kv GEMM 64x64 (M=2048, N=2048 over [wk|wv]^T):
//                                   LN->kh / bf16->vh; [1024,1088) q GEMM (M=256, N=1024): LN->qh
__global__ __launch_bounds__(256) void k_gemm_qkv(const u16* __restrict__ xn, const u16* __restrict__ wt,
                                                  u16* __restrict__ qh, u16* __restrict__ kh,
                                                  u16* __restrict__ vh) {
  __shared__ u16 As[64 * 128];   // 16 KB
  __shared__ u16 Bs[64 * 128];   // 16 KB
  const int bid = blockIdx.x;
  if (bid < 1024) {
    const int r0 = (bid >> 5) * 64, c0 = (bid & 31) * 64;
    const u16* BT = wt + (size_t)D * D;       // [wk^T | wv^T], 2048 rows
    if (c0 < 1024) gemm64<1, 128>(As, Bs, xn, BT, kh, r0, c0, c0, D, 0, 1024);
    else           gemm64<2, 128>(As, Bs, xn, BT, vh, r0, c0, c0 - 1024, D, 0, 1024);
  } else {
    const int q = bid - 1024;
    gemm64<1, 128>(As, Bs, xn, wt, qh, (q >> 4) * 64, (q & 15) * 64, (q & 15) * 64, D, 0, 1024);
  }
}

// output GEMM (round-6 form): 64 tiles (4x16 of 64x64) x split-K(2, slices of 512)
// -> atomicAdd into out (rows<256; out pre-initialized to x by k_pre)
__global__ __launch_bounds__(256) void k_gemm_o(const u16* __restrict__ attnb, const u16* __restrict__ wt,
                                                float* __restrict__ out) {
  __shared__ u16 As[64 * 64];    // 8 KB
  __shared__ u16 Bs[64 * 64];    // 8 KB
  const int s = blockIdx.x & 1, tile = blockIdx.x >> 1;
  gemm64<3, 64>(As, Bs, attnb, wt + (size_t)3 * D * D, out,
                (tile >> 4) * 64, (tile & 15) * 64, (tile & 15) * 64, D, s * 512, s * 512 + 512);
}

// ---- block-sparse attention: block = (head h, q-block b); kv rows {b+16j} (all bf16 inputs) ----
__global__ __launch_bounds__(256) void k_attn(const u16* __restrict__ qh, const u16* __restrict__ kh,
                                              const u16* __restrict__ vh, u16* __restrict__ attnb) {
  const int h = blockIdx.x >> 4, b = blockIdx.x & 15;
  __shared__ float q_s[16][68];
  __shared__ u16  k_u[128][72];                 // 144B row stride: 16B-aligned, conflict-light
  __shared__ u16  v_u[128][64];
  __shared__ float s_s[16][132];
  __shared__ float inv_den[16];
  const int t = threadIdx.x;

  {
    const int i = t >> 4, sub = t & 15;
    const u16x4 qq = *(const u16x4*)&qh[(size_t)(b * 16 + i) * D + h * 64 + sub * 4];
    q_s[i][sub * 4 + 0] = b2f(qq.x); q_s[i][sub * 4 + 1] = b2f(qq.y);
    q_s[i][sub * 4 + 2] = b2f(qq.z); q_s[i][sub * 4 + 3] = b2f(qq.w);
  }
#pragma unroll
  for (int it = 0; it < 4; ++it) {
    const int idx = t + it * 256;               // 1024 chunks of 8 u16 = 128 rows x 8
    const int j = idx >> 3, c = (idx & 7) * 8;
    const int kr = b + 16 * j;
    *(u32x4*)&k_u[j][c] = *(const u32x4*)&kh[(size_t)kr * D + h * 64 + c];
    *(u32x4*)&v_u[j][c] = *(const u32x4*)&vh[(size_t)kr * D + h * 64 + c];
  }
  __syncthreads();

  const int i = t >> 4;
  const int sub = t & 15;
#pragma unroll
  for (int jj = 0; jj < 8; ++jj) {
    const int j = sub + 16 * jj;
    float acc = 0.f;
#pragma unroll
    for (int d4 = 0; d4 < 16; ++d4) {
      const u16x4 kk = *(const u16x4*)&k_u[j][d4 * 4];
      acc += q_s[i][d4 * 4 + 0] * b2f(kk.x) + q_s[i][d4 * 4 + 1] * b2f(kk.y)
           + q_s[i][d4 * 4 + 2] * b2f(kk.z) + q_s[i][d4 * 4 + 3] * b2f(kk.w);
    }
    s_s[i][j] = acc * 0.125f;   // sm_scale = 1/sqrt(64)
  }
  __syncthreads();
  float m = -1e30f;
#pragma unroll
  for (int jj = 0; jj < 8; ++jj) m = fmaxf(m, s_s[i][sub + 16 * jj]);
  for (int off = 1; off < 16; off <<= 1) m = fmaxf(m, __shfl_xor(m, off, 64));
  float sum = 0.f;
#pragma unroll
  for (int jj = 0; jj < 8; ++jj) {
    const int j = sub + 16 * jj;
    const float p = __expf(s_s[i][j] - m);
    s_s[i][j] = p;
    sum += p;
  }
  for (int off = 1; off < 16; off <<= 1) sum += __shfl_xor(sum, off, 64);
  if (sub == 0) inv_den[i] = 1.0f / sum;
  __syncthreads();

  const int db = sub << 2;
  float a0 = 0, a1 = 0, a2 = 0, a3 = 0;
  for (int j = 0; j < 128; ++j) {
    const float p = s_s[i][j];
    const u16x4 vv = *(const u16x4*)&v_u[j][db];
    a0 += p * b2f(vv.x); a1 += p * b2f(vv.y); a2 += p * b2f(vv.z); a3 += p * b2f(vv.w);
  }
  const float inv = inv_den[i];
  u16x4 o;
  o.x = f2b(a0 * inv); o.y = f2b(a1 * inv); o.z = f2b(a2 * inv); o.w = f2b(a3 * inv);
  *(u16x4*)&attnb[(size_t)(b * 16 + i) * D + h * 64 + db] = o;
}

extern "C" void kernel_launch(void* const* d_in, const int* in_sizes, int n_in,
                              void* d_out, int out_size, void* d_ws, size_t ws_size,
                              hipStream_t stream) {
  const float* x  = (const float*)d_in[0];
  const float* wq = (const float*)d_in[1];
  const float* wk = (const float*)d_in[2];
  const float* wv = (const float*)d_in[3];
  const float* wo = (const float*)d_in[4];
  float* out = (float*)d_out;
  char* ws = (char*)d_ws;

  // ws layout (~21 MiB)
  u16* xn    = (u16*)(ws + 0);           // [2048][1024] bf16 LN(x)
  u16* wt    = (u16*)(ws + 4194304);     // [4][1024][1024] bf16 w^T (q,k,v,o)
  u16* qh    = (u16*)(ws + 12582912);    // [256][1024]  bf16 per-head-LN q
  u16* kh    = (u16*)(ws + 13107200);    // [2048][1024] bf16 per-head-LN k
  u16* vh    = (u16*)(ws + 17301504);    // [2048][1024] bf16 v
  u16* attnb = (u16*)(ws + 21495808);    // [256][1024]  bf16 attn output

  k_pre<<<dim3(6144), dim3(256), 0, stream>>>(x, wq, wk, wv, wo, xn, wt, out);
  k_gemm_qkv<<<dim3(1088), dim3(256), 0, stream>>>(xn, wt, qh, kh, vh);
  k_attn<<<dim3(256), dim3(256), 0, stream>>>(qh, kh, vh, attnb);
  k_gemm_o<<<dim3(128), dim3(256), 0, stream>>>(attnb, wt, out);
}

// Round 12
// 55.149 us; speedup vs baseline: 1.0480x; 1.0480x over previous
//
#include <hip/hip_runtime.h>
#include <hip/hip_bf16.h>

typedef unsigned short u16;
typedef __attribute__((ext_vector_type(8))) __bf16 bf16x8;
typedef __attribute__((ext_vector_type(4))) float f32x4;
typedef __attribute__((ext_vector_type(4))) unsigned short u16x4;
typedef __attribute__((ext_vector_type(4))) unsigned int u32x4;

#define DEV static __device__ __forceinline__

static constexpr int N = 2048, D = 1024;
static constexpr float EPS = 1e-5f;

DEV u16 f2b(float f) {
  union { float f; unsigned u; } x; x.f = f;
  unsigned r = x.u + 0x7FFFu + ((x.u >> 16) & 1u);   // RNE
  return (u16)(r >> 16);
}
DEV float b2f(u16 h) {
  union { unsigned u; float f; } x; x.u = ((unsigned)h) << 16;
  return x.f;
}

DEV void async16(const void* g, void* l) {
  __builtin_amdgcn_global_load_lds(
      (const __attribute__((address_space(1))) unsigned int*)g,
      (__attribute__((address_space(3))) unsigned int*)l, 16, 0, 0);
}

// ---- fused pre: blocks [0,2048) = LayerNorm(x)->bf16 AND out=x; [2048,6144) = transpose w -> bf16 [N][K]
__global__ __launch_bounds__(256) void k_pre(const float* __restrict__ x,
                                             const float* __restrict__ wq, const float* __restrict__ wk,
                                             const float* __restrict__ wv, const float* __restrict__ wo,
                                             u16* __restrict__ xn, u16* __restrict__ wt,
                                             float* __restrict__ out) {
  const int t = threadIdx.x;
  if (blockIdx.x < 2048) {
    const int row = blockIdx.x;
    const float4 v = ((const float4*)(x + (size_t)row * D))[t];
    ((float4*)(out + (size_t)row * D))[t] = v;      // residual base; rows<256 get atomic adds later
    float s  = v.x + v.y + v.z + v.w;
    float ss = v.x * v.x + v.y * v.y + v.z * v.z + v.w * v.w;
    __shared__ float red0[4], red1[4];
    for (int off = 32; off; off >>= 1) { s += __shfl_xor(s, off, 64); ss += __shfl_xor(ss, off, 64); }
    const int w = t >> 6, l = t & 63;
    if (l == 0) { red0[w] = s; red1[w] = ss; }
    __syncthreads();
    s  = red0[0] + red0[1] + red0[2] + red0[3];
    ss = red1[0] + red1[1] + red1[2] + red1[3];
    const float mu = s * (1.0f / D);
    const float var = ss * (1.0f / D) - mu * mu;
    const float rs = rsqrtf(var + EPS);
    u16x4 o;
    o.x = f2b((v.x - mu) * rs); o.y = f2b((v.y - mu) * rs);
    o.z = f2b((v.z - mu) * rs); o.w = f2b((v.w - mu) * rs);
    ((u16x4*)(xn + (size_t)row * D))[t] = o;
  } else {
    const int bid = blockIdx.x - 2048;
    const int z = bid >> 10, rem = bid & 1023;
    const float* src = z == 0 ? wq : z == 1 ? wk : z == 2 ? wv : wo;
    u16* dst = wt + (size_t)z * D * D;
    __shared__ float tile[32][33];
    const int k0 = (rem >> 5) * 32, n0 = (rem & 31) * 32;
    const int c = t & 31, r4 = t >> 5;
#pragma unroll
    for (int p = 0; p < 4; ++p) { int r = r4 + p * 8; tile[r][c] = src[(size_t)(k0 + r) * D + n0 + c]; }
    __syncthreads();
#pragma unroll
    for (int p = 0; p < 4; ++p) { int r = r4 + p * 8; dst[(size_t)(n0 + r) * D + k0 + c] = f2b(tile[c][r]); }
  }
}

// ---- LDS blocks ----
struct GS  { u16 As[64 * 64]; u16 Bs[64 * 64]; };    // 16 KB (gemm_o)
struct GSW { u16 As[64 * 64]; u16 Bs[128 * 64]; };   // 24 KB (qkv 64x128)

// ===== gemm64 (round-6 proven, gemm_o use): 64x64 tile, BK=64, single-buffer 2-barrier =====
// LDS swizzle: 16B chunk pos p of row R holds global chunk p^(R&7) (pre-swizzled source + XOR'd read).
// EPI: 3 = f32 atomicAdd
template<int EPI>
DEV void gemm64(GS& sh, const u16* __restrict__ A, const u16* __restrict__ BT,
                void* __restrict__ dst, int row0, int col0, int dcol0, int ldc,
                int kbeg, int kend) {
  constexpr int K = 1024, BK = 64;
  const int t = threadIdx.x;
  const int w = t >> 6, l = t & 63;
  const int wm = w << 4;
  const int fr = l & 15, kg = l >> 4;
  const int rq = kg << 2;

  f32x4 acc[4];
#pragma unroll
  for (int j = 0; j < 4; ++j) acc[j] = (f32x4){0.f, 0.f, 0.f, 0.f};

  const int r0s = t >> 3,          cs0 = (t & 7) ^ (r0s & 7);
  const int r1s = (t + 256) >> 3,  cs1 = (t & 7) ^ (r1s & 7);
  const u16* gA0 = A  + (size_t)(row0 + r0s) * K + cs0 * 8;
  const u16* gA1 = A  + (size_t)(row0 + r1s) * K + cs1 * 8;
  const u16* gB0 = BT + (size_t)(col0 + r0s) * K + cs0 * 8;
  const u16* gB1 = BT + (size_t)(col0 + r1s) * K + cs1 * 8;

  for (int k0 = kbeg; k0 < kend; k0 += BK) {
    async16(gA0 + k0, &sh.As[t * 8]);
    async16(gA1 + k0, &sh.As[(t + 256) * 8]);
    async16(gB0 + k0, &sh.Bs[t * 8]);
    async16(gB1 + k0, &sh.Bs[(t + 256) * 8]);
    __syncthreads();
    bf16x8 af[2], bf[4][2];
#pragma unroll
    for (int kk = 0; kk < 2; ++kk)
      af[kk] = *(const bf16x8*)&sh.As[(wm + fr) * BK + (((kk << 2) + kg) ^ (fr & 7)) * 8];
#pragma unroll
    for (int j = 0; j < 4; ++j)
#pragma unroll
      for (int kk = 0; kk < 2; ++kk)
        bf[j][kk] = *(const bf16x8*)&sh.Bs[(j * 16 + fr) * BK + (((kk << 2) + kg) ^ (fr & 7)) * 8];
#pragma unroll
    for (int kk = 0; kk < 2; ++kk)
#pragma unroll
      for (int j = 0; j < 4; ++j)
        acc[j] = __builtin_amdgcn_mfma_f32_16x16x32_bf16(af[kk], bf[j][kk], acc[j], 0, 0, 0);
    __syncthreads();
  }

  float* o = (float*)dst;
#pragma unroll
  for (int r = 0; r < 4; ++r) {
    const int row = row0 + wm + rq + r;
#pragma unroll
    for (int j = 0; j < 4; ++j)
      atomicAdd(&o[(size_t)row * ldc + dcol0 + j * 16 + fr], acc[j][r]);
  }
}

// ===== gemm64x128 (qkv): 64x128 tile (TWO heads), BK=64, same 2-barrier structure =====
// A staged once per K-step, reused for 128 cols -> 25% less staged bytes than two 64x64 tiles.
// LN epilogue per head half (j<4 = head at dcol0, j>=4 = head at dcol0+64); PLAIN = bf16 store.
template<bool LN>
DEV void gemm64x128(GSW& sh, const u16* __restrict__ A, const u16* __restrict__ BT,
                    u16* __restrict__ dst, int row0, int col0, int dcol0, int ldc) {
  constexpr int K = 1024, BK = 64;
  const int t = threadIdx.x;
  const int w = t >> 6, l = t & 63;
  const int wm = w << 4;                 // wave's 16 output rows
  const int fr = l & 15, kg = l >> 4;
  const int rq = kg << 2;

  f32x4 acc[8];
#pragma unroll
  for (int j = 0; j < 8; ++j) acc[j] = (f32x4){0.f, 0.f, 0.f, 0.f};

  // staging: A = 512 chunks (2/thread), B = 1024 chunks (4/thread); chunk c: row=c>>3,
  // stored pos=c&7, global chunk=(c&7)^(row&7)  [both-sides swizzle; (c+256k)&7 == c&7]
  const int ra0 = t >> 3,         ca0 = (t & 7) ^ (ra0 & 7);
  const int ra1 = (t + 256) >> 3, ca1 = (t & 7) ^ (ra1 & 7);
  const u16* gA0 = A + (size_t)(row0 + ra0) * K + ca0 * 8;
  const u16* gA1 = A + (size_t)(row0 + ra1) * K + ca1 * 8;
  const u16* gB[4];
#pragma unroll
  for (int p = 0; p < 4; ++p) {
    const int c = t + p * 256, row = c >> 3, gc = (c & 7) ^ (row & 7);
    gB[p] = BT + (size_t)(col0 + row) * K + gc * 8;
  }

  for (int k0 = 0; k0 < K; k0 += BK) {
    async16(gA0 + k0, &sh.As[t * 8]);
    async16(gA1 + k0, &sh.As[(t + 256) * 8]);
#pragma unroll
    for (int p = 0; p < 4; ++p) async16(gB[p] + k0, &sh.Bs[(t + p * 256) * 8]);
    __syncthreads();                       // drain vmcnt: staged data visible
    bf16x8 af[2], bf[8][2];
#pragma unroll
    for (int kk = 0; kk < 2; ++kk)
      af[kk] = *(const bf16x8*)&sh.As[(wm + fr) * BK + (((kk << 2) + kg) ^ (fr & 7)) * 8];
#pragma unroll
    for (int j = 0; j < 8; ++j)
#pragma unroll
      for (int kk = 0; kk < 2; ++kk)
        bf[j][kk] = *(const bf16x8*)&sh.Bs[(j * 16 + fr) * BK + (((kk << 2) + kg) ^ (fr & 7)) * 8];
#pragma unroll
    for (int kk = 0; kk < 2; ++kk)
#pragma unroll
      for (int j = 0; j < 8; ++j)
        acc[j] = __builtin_amdgcn_mfma_f32_16x16x32_bf16(af[kk], bf[j][kk], acc[j], 0, 0, 0);
    __syncthreads();                       // LDS reads done before next stage overwrites
  }

  // C/D layout: col = j*16 + fr, row = wm + rq + r
  if constexpr (LN) {
    // per-row LN per head half; width-16 shuffle reduce
    float ps[2][4], pss[2][4];
#pragma unroll
    for (int h2 = 0; h2 < 2; ++h2)
#pragma unroll
      for (int r = 0; r < 4; ++r) {
        float s = 0.f, ss = 0.f;
#pragma unroll
        for (int j = h2 * 4; j < h2 * 4 + 4; ++j) { const float v = acc[j][r]; s += v; ss += v * v; }
        ps[h2][r] = s; pss[h2][r] = ss;
      }
    for (int off = 1; off < 16; off <<= 1)
#pragma unroll
      for (int h2 = 0; h2 < 2; ++h2)
#pragma unroll
        for (int r = 0; r < 4; ++r) {
          ps[h2][r]  += __shfl_xor(ps[h2][r],  off, 16);
          pss[h2][r] += __shfl_xor(pss[h2][r], off, 16);
        }
#pragma unroll
    for (int r = 0; r < 4; ++r) {
      const int row = row0 + wm + rq + r;
#pragma unroll
      for (int h2 = 0; h2 < 2; ++h2) {
        const float mu = ps[h2][r] * (1.0f / 64);
        const float rs = rsqrtf(pss[h2][r] * (1.0f / 64) - mu * mu + EPS);
#pragma unroll
        for (int j = h2 * 4; j < h2 * 4 + 4; ++j)
          dst[(size_t)row * ldc + dcol0 + j * 16 + fr] = f2b((acc[j][r] - mu) * rs);
      }
    }
  } else {
#pragma unroll
    for (int r = 0; r < 4; ++r) {
      const int row = row0 + wm + rq + r;
#pragma unroll
      for (int j = 0; j < 8; ++j)
        dst[(size_t)row * ldc + dcol0 + j * 16 + fr] = f2b(acc[j][r]);
    }
  }
}

// fused QKV: [0,512) kv GEMM 64x128 tiles (M=2048, N=2048 over [wk|wv]^T): LN->kh / bf16->vh;
//            [512,544) q GEMM 64x128 (M=256, N=1024): LN->qh
__global__ __launch_bounds__(256) void k_gemm_qkv(const u16* __restrict__ xn, const u16* __restrict__ wt,
                                                  u16* __restrict__ qh, u16* __restrict__ kh,
                                                  u16* __restrict__ vh) {
  __shared__ GSW sh;
  const int bid = blockIdx.x;
  if (bid < 512) {
    const int r0 = (bid >> 4) * 64, c0 = (bid & 15) * 128;
    const u16* BT = wt + (size_t)D * D;       // [wk^T | wv^T], 2048 rows
    if (c0 < 1024) gemm64x128<true >(sh, xn, BT, kh, r0, c0, c0, D);
    else           gemm64x128<false>(sh, xn, BT, vh, r0, c0, c0 - 1024, D);
  } else {
    const int q = bid - 512;
    gemm64x128<true>(sh, xn, wt, qh, (q >> 3) * 64, (q & 7) * 128, (q & 7) * 128, D);
  }
}

// output GEMM (round-6 form): 64 tiles (4x16 of 64x64) x split-K(2, slices of 512)
// -> atomicAdd into out (rows<256; out pre-initialized to x by k_pre)
__global__ __launch_bounds__(256) void k_gemm_o(const u16* __restrict__ attnb, const u16* __restrict__ wt,
                                                float* __restrict__ out) {
  __shared__ GS sh;
  const int s = blockIdx.x & 1, tile = blockIdx.x >> 1;
  gemm64<3>(sh, attnb, wt + (size_t)3 * D * D, out,
            (tile >> 4) * 64, (tile & 15) * 64, (tile & 15) * 64, D, s * 512, s * 512 + 512);
}

// ---- block-sparse attention: block = (head h, q-block b); kv rows {b+16j} (all bf16 inputs) ----
__global__ __launch_bounds__(256) void k_attn(const u16* __restrict__ qh, const u16* __restrict__ kh,
                                              const u16* __restrict__ vh, u16* __restrict__ attnb) {
  const int h = blockIdx.x >> 4, b = blockIdx.x & 15;
  __shared__ float q_s[16][68];
  __shared__ u16  k_u[128][72];                 // 144B row stride: 16B-aligned, conflict-light
  __shared__ u16  v_u[128][64];
  __shared__ float s_s[16][132];
  __shared__ float inv_den[16];
  const int t = threadIdx.x;

  {
    const int i = t >> 4, sub = t & 15;
    const u16x4 qq = *(const u16x4*)&qh[(size_t)(b * 16 + i) * D + h * 64 + sub * 4];
    q_s[i][sub * 4 + 0] = b2f(qq.x); q_s[i][sub * 4 + 1] = b2f(qq.y);
    q_s[i][sub * 4 + 2] = b2f(qq.z); q_s[i][sub * 4 + 3] = b2f(qq.w);
  }
#pragma unroll
  for (int it = 0; it < 4; ++it) {
    const int idx = t + it * 256;               // 1024 chunks of 8 u16 = 128 rows x 8
    const int j = idx >> 3, c = (idx & 7) * 8;
    const int kr = b + 16 * j;
    *(u32x4*)&k_u[j][c] = *(const u32x4*)&kh[(size_t)kr * D + h * 64 + c];
    *(u32x4*)&v_u[j][c] = *(const u32x4*)&vh[(size_t)kr * D + h * 64 + c];
  }
  __syncthreads();

  const int i = t >> 4;
  const int sub = t & 15;
#pragma unroll
  for (int jj = 0; jj < 8; ++jj) {
    const int j = sub + 16 * jj;
    float acc = 0.f;
#pragma unroll
    for (int d4 = 0; d4 < 16; ++d4) {
      const u16x4 kk = *(const u16x4*)&k_u[j][d4 * 4];
      acc += q_s[i][d4 * 4 + 0] * b2f(kk.x) + q_s[i][d4 * 4 + 1] * b2f(kk.y)
           + q_s[i][d4 * 4 + 2] * b2f(kk.z) + q_s[i][d4 * 4 + 3] * b2f(kk.w);
    }
    s_s[i][j] = acc * 0.125f;   // sm_scale = 1/sqrt(64)
  }
  __syncthreads();
  float m = -1e30f;
#pragma unroll
  for (int jj = 0; jj < 8; ++jj) m = fmaxf(m, s_s[i][sub + 16 * jj]);
  for (int off = 1; off < 16; off <<= 1) m = fmaxf(m, __shfl_xor(m, off, 64));
  float sum = 0.f;
#pragma unroll
  for (int jj = 0; jj < 8; ++jj) {
    const int j = sub + 16 * jj;
    const float p = __expf(s_s[i][j] - m);
    s_s[i][j] = p;
    sum += p;
  }
  for (int off = 1; off < 16; off <<= 1) sum += __shfl_xor(sum, off, 64);
  if (sub == 0) inv_den[i] = 1.0f / sum;
  __syncthreads();

  const int db = sub << 2;
  float a0 = 0, a1 = 0, a2 = 0, a3 = 0;
  for (int j = 0; j < 128; ++j) {
    const float p = s_s[i][j];
    const u16x4 vv = *(const u16x4*)&v_u[j][db];
    a0 += p * b2f(vv.x); a1 += p * b2f(vv.y); a2 += p * b2f(vv.z); a3 += p * b2f(vv.w);
  }
  const float inv = inv_den[i];
  u16x4 o;
  o.x = f2b(a0 * inv); o.y = f2b(a1 * inv); o.z = f2b(a2 * inv); o.w = f2b(a3 * inv);
  *(u16x4*)&attnb[(size_t)(b * 16 + i) * D + h * 64 + db] = o;
}

extern "C" void kernel_launch(void* const* d_in, const int* in_sizes, int n_in,
                              void* d_out, int out_size, void* d_ws, size_t ws_size,
                              hipStream_t stream) {
  const float* x  = (const float*)d_in[0];
  const float* wq = (const float*)d_in[1];
  const float* wk = (const float*)d_in[2];
  const float* wv = (const float*)d_in[3];
  const float* wo = (const float*)d_in[4];
  float* out = (float*)d_out;
  char* ws = (char*)d_ws;

  // ws layout (~21 MiB)
  u16* xn    = (u16*)(ws + 0);           // [2048][1024] bf16 LN(x)
  u16* wt    = (u16*)(ws + 4194304);     // [4][1024][1024] bf16 w^T (q,k,v,o)
  u16* qh    = (u16*)(ws + 12582912);    // [256][1024]  bf16 per-head-LN q
  u16* kh    = (u16*)(ws + 13107200);    // [2048][1024] bf16 per-head-LN k
  u16* vh    = (u16*)(ws + 17301504);    // [2048][1024] bf16 v
  u16* attnb = (u16*)(ws + 21495808);    // [256][1024]  bf16 attn output

  k_pre<<<dim3(6144), dim3(256), 0, stream>>>(x, wq, wk, wv, wo, xn, wt, out);
  k_gemm_qkv<<<dim3(544), dim3(256), 0, stream>>>(xn, wt, qh, kh, vh);
  k_attn<<<dim3(256), dim3(256), 0, stream>>>(qh, kh, vh, attnb);
  k_gemm_o<<<dim3(128), dim3(256), 0, stream>>>(attnb, wt, out);
}

// Round 13
// 54.783 us; speedup vs baseline: 1.0550x; 1.0067x over previous
//
#include <hip/hip_runtime.h>
#include <hip/hip_bf16.h>

typedef unsigned short u16;
typedef __attribute__((ext_vector_type(8))) __bf16 bf16x8;
typedef __attribute__((ext_vector_type(4))) float f32x4;
typedef __attribute__((ext_vector_type(4))) unsigned short u16x4;
typedef __attribute__((ext_vector_type(4))) unsigned int u32x4;

#define DEV static __device__ __forceinline__

static constexpr int N = 2048, D = 1024;
static constexpr float EPS = 1e-5f;

DEV u16 f2b(float f) {
  union { float f; unsigned u; } x; x.f = f;
  unsigned r = x.u + 0x7FFFu + ((x.u >> 16) & 1u);   // RNE
  return (u16)(r >> 16);
}
DEV float b2f(u16 h) {
  union { unsigned u; float f; } x; x.u = ((unsigned)h) << 16;
  return x.f;
}

DEV void async16(const void* g, void* l) {
  __builtin_amdgcn_global_load_lds(
      (const __attribute__((address_space(1))) unsigned int*)g,
      (__attribute__((address_space(3))) unsigned int*)l, 16, 0, 0);
}

// ---- fused pre (round-6 form): blocks [0,2048) = LayerNorm(x)->bf16 AND out=x;
//                                [2048,6144) = transpose w -> bf16 [N][K]
__global__ __launch_bounds__(256) void k_pre(const float* __restrict__ x,
                                             const float* __restrict__ wq, const float* __restrict__ wk,
                                             const float* __restrict__ wv, const float* __restrict__ wo,
                                             u16* __restrict__ xn, u16* __restrict__ wt,
                                             float* __restrict__ out) {
  const int t = threadIdx.x;
  if (blockIdx.x < 2048) {
    const int row = blockIdx.x;
    const float4 v = ((const float4*)(x + (size_t)row * D))[t];
    ((float4*)(out + (size_t)row * D))[t] = v;      // residual base; rows<256 get atomic adds later
    float s  = v.x + v.y + v.z + v.w;
    float ss = v.x * v.x + v.y * v.y + v.z * v.z + v.w * v.w;
    __shared__ float red0[4], red1[4];
    for (int off = 32; off; off >>= 1) { s += __shfl_xor(s, off, 64); ss += __shfl_xor(ss, off, 64); }
    const int w = t >> 6, l = t & 63;
    if (l == 0) { red0[w] = s; red1[w] = ss; }
    __syncthreads();
    s  = red0[0] + red0[1] + red0[2] + red0[3];
    ss = red1[0] + red1[1] + red1[2] + red1[3];
    const float mu = s * (1.0f / D);
    const float var = ss * (1.0f / D) - mu * mu;
    const float rs = rsqrtf(var + EPS);
    u16x4 o;
    o.x = f2b((v.x - mu) * rs); o.y = f2b((v.y - mu) * rs);
    o.z = f2b((v.z - mu) * rs); o.w = f2b((v.w - mu) * rs);
    ((u16x4*)(xn + (size_t)row * D))[t] = o;
  } else {
    const int bid = blockIdx.x - 2048;
    const int z = bid >> 10, rem = bid & 1023;
    const float* src = z == 0 ? wq : z == 1 ? wk : z == 2 ? wv : wo;
    u16* dst = wt + (size_t)z * D * D;
    __shared__ float tile[32][33];
    const int k0 = (rem >> 5) * 32, n0 = (rem & 31) * 32;
    const int c = t & 31, r4 = t >> 5;
#pragma unroll
    for (int p = 0; p < 4; ++p) { int r = r4 + p * 8; tile[r][c] = src[(size_t)(k0 + r) * D + n0 + c]; }
    __syncthreads();
#pragma unroll
    for (int p = 0; p < 4; ++p) { int r = r4 + p * 8; dst[(size_t)(n0 + r) * D + k0 + c] = f2b(tile[c][r]); }
  }
}

// ---- LDS blocks ----
struct GS  { u16 As[64 * 64]; u16 Bs[64 * 64]; };        // 16 KB (gemm_o, single-buffer)
struct GSQ { u16 As[2][64 * 64]; u16 Bs[2][64 * 64]; };  // 32 KB (qkv, double-buffer)

// ===== gemm64p (qkv): 64x64 tile, BK=64, dbuf + counted vmcnt + raw s_barrier (T4 at high occ) ====
// Per stage: 4 global_load_lds / wave. Loop: stage NEXT (outstanding=8) -> vmcnt(4) (cur's retired,
// next's stay in flight across compute) -> barrier -> compute cur -> barrier (reads done) -> swap.
// LDS swizzle: 16B chunk pos p of row R holds global chunk p^(R&7) (pre-swizzled src + XOR'd read).
// EPI: 1 = per-row LN over the 64 cols -> bf16; 2 = bf16 store
template<int EPI>
DEV void gemm64p(GSQ& sh, const u16* __restrict__ A, const u16* __restrict__ BT,
                 u16* __restrict__ dst, int row0, int col0, int dcol0, int ldc) {
  constexpr int K = 1024, BK = 64, NT = K / BK;
  const int t = threadIdx.x;
  const int w = t >> 6, l = t & 63;
  const int wm = w << 4;                 // wave's 16 output rows
  const int fr = l & 15, kg = l >> 4;
  const int rq = kg << 2;

  f32x4 acc[4];
#pragma unroll
  for (int j = 0; j < 4; ++j) acc[j] = (f32x4){0.f, 0.f, 0.f, 0.f};

  const int r0s = t >> 3,          cs0 = (t & 7) ^ (r0s & 7);
  const int r1s = (t + 256) >> 3,  cs1 = (t & 7) ^ (r1s & 7);   // (t+256)&7 == t&7
  const u16* gA0 = A  + (size_t)(row0 + r0s) * K + cs0 * 8;
  const u16* gA1 = A  + (size_t)(row0 + r1s) * K + cs1 * 8;
  const u16* gB0 = BT + (size_t)(col0 + r0s) * K + cs0 * 8;
  const u16* gB1 = BT + (size_t)(col0 + r1s) * K + cs1 * 8;
  const int ld0 = t * 8, ld1 = (t + 256) * 8;

  // prologue: stage tile 0 into buf 0 (4 loads in flight)
  async16(gA0 + 0, &sh.As[0][ld0]);
  async16(gA1 + 0, &sh.As[0][ld1]);
  async16(gB0 + 0, &sh.Bs[0][ld0]);
  async16(gB1 + 0, &sh.Bs[0][ld1]);

  for (int it = 0; it < NT; ++it) {
    const int cur = it & 1;
    if (it + 1 < NT) {
      const int k0 = (it + 1) * BK, o = cur ^ 1;
      async16(gA0 + k0, &sh.As[o][ld0]);
      async16(gA1 + k0, &sh.As[o][ld1]);
      async16(gB0 + k0, &sh.Bs[o][ld0]);
      async16(gB1 + k0, &sh.Bs[o][ld1]);
      asm volatile("s_waitcnt vmcnt(4)" ::: "memory");   // cur's 4 retired; next's 4 in flight
    } else {
      asm volatile("s_waitcnt vmcnt(0)" ::: "memory");   // final tile: drain
    }
    __builtin_amdgcn_s_barrier();        // all waves' cur data visible in LDS
    bf16x8 af[2], bf[4][2];
#pragma unroll
    for (int kk = 0; kk < 2; ++kk)
      af[kk] = *(const bf16x8*)&sh.As[cur][(wm + fr) * BK + (((kk << 2) + kg) ^ (fr & 7)) * 8];
#pragma unroll
    for (int j = 0; j < 4; ++j)
#pragma unroll
      for (int kk = 0; kk < 2; ++kk)
        bf[j][kk] = *(const bf16x8*)&sh.Bs[cur][(j * 16 + fr) * BK + (((kk << 2) + kg) ^ (fr & 7)) * 8];
#pragma unroll
    for (int kk = 0; kk < 2; ++kk)
#pragma unroll
      for (int j = 0; j < 4; ++j)
        acc[j] = __builtin_amdgcn_mfma_f32_16x16x32_bf16(af[kk], bf[j][kk], acc[j], 0, 0, 0);
    __builtin_amdgcn_s_barrier();        // all waves done reading cur before it is restaged
  }

  // C/D layout: col = j*16 + fr, row = wm + rq + r
  if constexpr (EPI == 1) {
    float ps[4], pss[4];
#pragma unroll
    for (int r = 0; r < 4; ++r) {
      float s = 0.f, ss = 0.f;
#pragma unroll
      for (int j = 0; j < 4; ++j) { const float v = acc[j][r]; s += v; ss += v * v; }
      ps[r] = s; pss[r] = ss;
    }
    for (int off = 1; off < 16; off <<= 1)
#pragma unroll
      for (int r = 0; r < 4; ++r) {
        ps[r]  += __shfl_xor(ps[r],  off, 16);
        pss[r] += __shfl_xor(pss[r], off, 16);
      }
#pragma unroll
    for (int r = 0; r < 4; ++r) {
      const float mu = ps[r] * (1.0f / 64);
      const float rs = rsqrtf(pss[r] * (1.0f / 64) - mu * mu + EPS);
      const int row = row0 + wm + rq + r;
#pragma unroll
      for (int j = 0; j < 4; ++j)
        dst[(size_t)row * ldc + dcol0 + j * 16 + fr] = f2b((acc[j][r] - mu) * rs);
    }
  } else {
#pragma unroll
    for (int r = 0; r < 4; ++r) {
      const int row = row0 + wm + rq + r;
#pragma unroll
      for (int j = 0; j < 4; ++j)
        dst[(size_t)row * ldc + dcol0 + j * 16 + fr] = f2b(acc[j][r]);
    }
  }
}

// ===== gemm64 (round-6 proven, gemm_o): 64x64, BK=64, single-buffer 2-barrier, atomicAdd =====
DEV void gemm64o(GS& sh, const u16* __restrict__ A, const u16* __restrict__ BT,
                 float* __restrict__ o, int row0, int col0, int dcol0, int ldc,
                 int kbeg, int kend) {
  constexpr int K = 1024, BK = 64;
  const int t = threadIdx.x;
  const int w = t >> 6, l = t & 63;
  const int wm = w << 4;
  const int fr = l & 15, kg = l >> 4;
  const int rq = kg << 2;

  f32x4 acc[4];
#pragma unroll
  for (int j = 0; j < 4; ++j) acc[j] = (f32x4){0.f, 0.f, 0.f, 0.f};

  const int r0s = t >> 3,          cs0 = (t & 7) ^ (r0s & 7);
  const int r1s = (t + 256) >> 3,  cs1 = (t & 7) ^ (r1s & 7);
  const u16* gA0 = A  + (size_t)(row0 + r0s) * K + cs0 * 8;
  const u16* gA1 = A  + (size_t)(row0 + r1s) * K + cs1 * 8;
  const u16* gB0 = BT + (size_t)(col0 + r0s) * K + cs0 * 8;
  const u16* gB1 = BT + (size_t)(col0 + r1s) * K + cs1 * 8;

  for (int k0 = kbeg; k0 < kend; k0 += BK) {
    async16(gA0 + k0, &sh.As[t * 8]);
    async16(gA1 + k0, &sh.As[(t + 256) * 8]);
    async16(gB0 + k0, &sh.Bs[t * 8]);
    async16(gB1 + k0, &sh.Bs[(t + 256) * 8]);
    __syncthreads();
    bf16x8 af[2], bf[4][2];
#pragma unroll
    for (int kk = 0; kk < 2; ++kk)
      af[kk] = *(const bf16x8*)&sh.As[(wm + fr) * BK + (((kk << 2) + kg) ^ (fr & 7)) * 8];
#pragma unroll
    for (int j = 0; j < 4; ++j)
#pragma unroll
      for (int kk = 0; kk < 2; ++kk)
        bf[j][kk] = *(const bf16x8*)&sh.Bs[(j * 16 + fr) * BK + (((kk << 2) + kg) ^ (fr & 7)) * 8];
#pragma unroll
    for (int kk = 0; kk < 2; ++kk)
#pragma unroll
      for (int j = 0; j < 4; ++j)
        acc[j] = __builtin_amdgcn_mfma_f32_16x16x32_bf16(af[kk], bf[j][kk], acc[j], 0, 0, 0);
    __syncthreads();
  }

#pragma unroll
  for (int r = 0; r < 4; ++r) {
    const int row = row0 + wm + rq + r;
#pragma unroll
    for (int j = 0; j < 4; ++j)
      atomicAdd(&o[(size_t)row * ldc + dcol0 + j * 16 + fr], acc[j][r]);
  }
}

// fused QKV (round-6 grid): [0,1024) kv GEMM 64x64 (M=2048, N=2048 over [wk|wv]^T): LN->kh / bf16->vh;
//                           [1024,1088) q GEMM (M=256, N=1024): LN->qh
__global__ __launch_bounds__(256) void k_gemm_qkv(const u16* __restrict__ xn, const u16* __restrict__ wt,
                                                  u16* __restrict__ qh, u16* __restrict__ kh,
                                                  u16* __restrict__ vh) {
  __shared__ GSQ sh;
  const int bid = blockIdx.x;
  if (bid < 1024) {
    const int r0 = (bid >> 5) * 64, c0 = (bid & 31) * 64;
    const u16* BT = wt + (size_t)D * D;       // [wk^T | wv^T], 2048 rows
    if (c0 < 1024) gemm64p<1>(sh, xn, BT, kh, r0, c0, c0, D);
    else           gemm64p<2>(sh, xn, BT, vh, r0, c0, c0 - 1024, D);
  } else {
    const int q = bid - 1024;
    gemm64p<1>(sh, xn, wt, qh, (q >> 4) * 64, (q & 15) * 64, (q & 15) * 64, D);
  }
}

// output GEMM (round-6 form): 64 tiles (4x16 of 64x64) x split-K(2, slices of 512)
// -> atomicAdd into out (rows<256; out pre-initialized to x by k_pre)
__global__ __launch_bounds__(256) void k_gemm_o(const u16* __restrict__ attnb, const u16* __restrict__ wt,
                                                float* __restrict__ out) {
  __shared__ GS sh;
  const int s = blockIdx.x & 1, tile = blockIdx.x >> 1;
  gemm64o(sh, attnb, wt + (size_t)3 * D * D, out,
          (tile >> 4) * 64, (tile & 15) * 64, (tile & 15) * 64, D, s * 512, s * 512 + 512);
}

// ---- block-sparse attention: block = (head h, q-block b); kv rows {b+16j} (all bf16 inputs) ----
__global__ __launch_bounds__(256) void k_attn(const u16* __restrict__ qh, const u16* __restrict__ kh,
                                              const u16* __restrict__ vh, u16* __restrict__ attnb) {
  const int h = blockIdx.x >> 4, b = blockIdx.x & 15;
  __shared__ float q_s[16][68];
  __shared__ u16  k_u[128][72];                 // 144B row stride: 16B-aligned, conflict-light
  __shared__ u16  v_u[128][64];
  __shared__ float s_s[16][132];
  __shared__ float inv_den[16];
  const int t = threadIdx.x;

  {
    const int i = t >> 4, sub = t & 15;
    const u16x4 qq = *(const u16x4*)&qh[(size_t)(b * 16 + i) * D + h * 64 + sub * 4];
    q_s[i][sub * 4 + 0] = b2f(qq.x); q_s[i][sub * 4 + 1] = b2f(qq.y);
    q_s[i][sub * 4 + 2] = b2f(qq.z); q_s[i][sub * 4 + 3] = b2f(qq.w);
  }
#pragma unroll
  for (int it = 0; it < 4; ++it) {
    const int idx = t + it * 256;               // 1024 chunks of 8 u16 = 128 rows x 8
    const int j = idx >> 3, c = (idx & 7) * 8;
    const int kr = b + 16 * j;
    *(u32x4*)&k_u[j][c] = *(const u32x4*)&kh[(size_t)kr * D + h * 64 + c];
    *(u32x4*)&v_u[j][c] = *(const u32x4*)&vh[(size_t)kr * D + h * 64 + c];
  }
  __syncthreads();

  const int i = t >> 4;
  const int sub = t & 15;
#pragma unroll
  for (int jj = 0; jj < 8; ++jj) {
    const int j = sub + 16 * jj;
    float acc = 0.f;
#pragma unroll
    for (int d4 = 0; d4 < 16; ++d4) {
      const u16x4 kk = *(const u16x4*)&k_u[j][d4 * 4];
      acc += q_s[i][d4 * 4 + 0] * b2f(kk.x) + q_s[i][d4 * 4 + 1] * b2f(kk.y)
           + q_s[i][d4 * 4 + 2] * b2f(kk.z) + q_s[i][d4 * 4 + 3] * b2f(kk.w);
    }
    s_s[i][j] = acc * 0.125f;   // sm_scale = 1/sqrt(64)
  }
  __syncthreads();
  float m = -1e30f;
#pragma unroll
  for (int jj = 0; jj < 8; ++jj) m = fmaxf(m, s_s[i][sub + 16 * jj]);
  for (int off = 1; off < 16; off <<= 1) m = fmaxf(m, __shfl_xor(m, off, 64));
  float sum = 0.f;
#pragma unroll
  for (int jj = 0; jj < 8; ++jj) {
    const int j = sub + 16 * jj;
    const float p = __expf(s_s[i][j] - m);
    s_s[i][j] = p;
    sum += p;
  }
  for (int off = 1; off < 16; off <<= 1) sum += __shfl_xor(sum, off, 64);
  if (sub == 0) inv_den[i] = 1.0f / sum;
  __syncthreads();

  const int db = sub << 2;
  float a0 = 0, a1 = 0, a2 = 0, a3 = 0;
  for (int j = 0; j < 128; ++j) {
    const float p = s_s[i][j];
    const u16x4 vv = *(const u16x4*)&v_u[j][db];
    a0 += p * b2f(vv.x); a1 += p * b2f(vv.y); a2 += p * b2f(vv.z); a3 += p * b2f(vv.w);
  }
  const float inv = inv_den[i];
  u16x4 o;
  o.x = f2b(a0 * inv); o.y = f2b(a1 * inv); o.z = f2b(a2 * inv); o.w = f2b(a3 * inv);
  *(u16x4*)&attnb[(size_t)(b * 16 + i) * D + h * 64 + db] = o;
}

extern "C" void kernel_launch(void* const* d_in, const int* in_sizes, int n_in,
                              void* d_out, int out_size, void* d_ws, size_t ws_size,
                              hipStream_t stream) {
  const float* x  = (const float*)d_in[0];
  const float* wq = (const float*)d_in[1];
  const float* wk = (const float*)d_in[2];
  const float* wv = (const float*)d_in[3];
  const float* wo = (const float*)d_in[4];
  float* out = (float*)d_out;
  char* ws = (char*)d_ws;

  // ws layout (~21 MiB)
  u16* xn    = (u16*)(ws + 0);           // [2048][1024] bf16 LN(x)
  u16* wt    = (u16*)(ws + 4194304);     // [4][1024][1024] bf16 w^T (q,k,v,o)
  u16* qh    = (u16*)(ws + 12582912);    // [256][1024]  bf16 per-head-LN q
  u16* kh    = (u16*)(ws + 13107200);    // [2048][1024] bf16 per-head-LN k
  u16* vh    = (u16*)(ws + 17301504);    // [2048][1024] bf16 v
  u16* attnb = (u16*)(ws + 21495808);    // [256][1024]  bf16 attn output

  k_pre<<<dim3(6144), dim3(256), 0, stream>>>(x, wq, wk, wv, wo, xn, wt, out);
  k_gemm_qkv<<<dim3(1088), dim3(256), 0, stream>>>(xn, wt, qh, kh, vh);
  k_attn<<<dim3(256), dim3(256), 0, stream>>>(qh, kh, vh, attnb);
  k_gemm_o<<<dim3(128), dim3(256), 0, stream>>>(attnb, wt, out);
}